// Round 1
// baseline (744.525 us; speedup 1.0000x reference)
//
#include <hip/hip_runtime.h>

typedef __bf16 bf16x8 __attribute__((ext_vector_type(8)));
typedef float  f32x4  __attribute__((ext_vector_type(4)));

#define MFMA16(a, b, c) __builtin_amdgcn_mfma_f32_16x16x32_bf16((a), (b), (c), 0, 0, 0)

static constexpr int Cch = 128;   // channels
static constexpr int Nvox = 8192; // D*H*W = 8*32*32

// ---------------- K1: GroupNorm statistics: one block per (b,g), 16 blocks ----
__global__ __launch_bounds__(256) void gn_stats_k(const float* __restrict__ x,
                                                  float* __restrict__ stats) {
  // bg = b*8+g; group covers 16 channels * 8192 voxels, contiguous in memory
  const float* base = x + (size_t)blockIdx.x * 16 * Nvox;
  float s = 0.f, ss = 0.f;
  for (int i = threadIdx.x; i < 16 * Nvox; i += 256) {
    float v = base[i];
    s += v; ss += v * v;
  }
#pragma unroll
  for (int off = 32; off; off >>= 1) {
    s  += __shfl_down(s, off);
    ss += __shfl_down(ss, off);
  }
  __shared__ float rb[4], rbss[4];
  if ((threadIdx.x & 63) == 0) {
    rb[threadIdx.x >> 6] = s;
    rbss[threadIdx.x >> 6] = ss;
  }
  __syncthreads();
  if (threadIdx.x == 0) {
    float S = rb[0] + rb[1] + rb[2] + rb[3];
    float SS = rbss[0] + rbss[1] + rbss[2] + rbss[3];
    const float invn = 1.f / (16.f * Nvox);
    float mean = S * invn;
    float var = SS * invn - mean * mean;
    stats[blockIdx.x] = mean;            // mean[16]
    stats[16 + blockIdx.x] = rsqrtf(var + 1e-5f); // rstd[16]
  }
}

// ---------------- K2: weight f32 -> bf16 ----------------
__global__ __launch_bounds__(256) void conv_w_k(const float* __restrict__ wq,
                                                const float* __restrict__ wp,
                                                __bf16* __restrict__ wqb,
                                                __bf16* __restrict__ wpb) {
  int i = blockIdx.x * 256 + threadIdx.x;
  if (i < 384 * 128) wqb[i] = (__bf16)wq[i];
  if (i < 128 * 128) wpb[i] = (__bf16)wp[i];
}

// ---------------- K3: normalize + transpose to xn[b][n][c] (bf16) ------------
__global__ __launch_bounds__(256) void gn_apply_k(const float* __restrict__ x,
                                                  const float* __restrict__ gamma,
                                                  const float* __restrict__ beta,
                                                  const float* __restrict__ stats,
                                                  __bf16* __restrict__ xn) {
  __shared__ __bf16 t[64][136]; // 64 n-rows x 128 c, padded stride 136 (272B, 16B-mult)
  int b = blockIdx.x >> 7;
  int n0 = (blockIdx.x & 127) << 6;
  const float* xb = x + (size_t)b * Cch * Nvox;
  for (int i = threadIdx.x; i < 128 * 64; i += 256) {
    int c = i >> 6, nl = i & 63;
    int g = c >> 4;
    float mean = stats[b * 8 + g];
    float rstd = stats[16 + b * 8 + g];
    float v = xb[(size_t)c * Nvox + n0 + nl];
    t[nl][c] = (__bf16)((v - mean) * rstd * gamma[c] + beta[c]);
  }
  __syncthreads();
  __bf16* outb = xn + (size_t)b * Nvox * Cch;
  for (int i = threadIdx.x; i < 64 * 16; i += 256) {
    int row = i >> 4, ch = (i & 15) << 3;
    *reinterpret_cast<bf16x8*>(&outb[(size_t)(n0 + row) * Cch + ch]) =
        *reinterpret_cast<const bf16x8*>(&t[row][ch]);
  }
}

// ---------------- K4: QKV GEMM (MFMA bf16) -----------------------------------
// out tiles: D[16 o x 16 n]; q,k stored [b][n][c]; v stored transposed [b][c][n]
__global__ __launch_bounds__(256) void qkv_k(const __bf16* __restrict__ xn,
                                             const __bf16* __restrict__ wq,
                                             const float* __restrict__ b_qkv,
                                             __bf16* __restrict__ q,
                                             __bf16* __restrict__ k,
                                             __bf16* __restrict__ vt) {
  int id = blockIdx.x;               // 2 * 6 * 128 blocks
  int b = id / 768;
  int rr = id % 768;
  int o0 = (rr >> 7) * 64;
  int n0 = (rr & 127) * 64;
  int w = threadIdx.x >> 6, l = threadIdx.x & 63;
  int lr = l & 15, lh = l >> 4;
  int ow = o0 + w * 16;

  bf16x8 a[4];
#pragma unroll
  for (int kc = 0; kc < 4; kc++)
    a[kc] = *reinterpret_cast<const bf16x8*>(&wq[(size_t)(ow + lr) * 128 + kc * 32 + lh * 8]);

  const __bf16* xb = xn + (size_t)b * Nvox * Cch;
#pragma unroll
  for (int ns = 0; ns < 4; ns++) {
    f32x4 acc = {0.f, 0.f, 0.f, 0.f};
#pragma unroll
    for (int kc = 0; kc < 4; kc++) {
      bf16x8 bf = *reinterpret_cast<const bf16x8*>(
          &xb[(size_t)(n0 + ns * 16 + lr) * Cch + kc * 32 + lh * 8]);
      acc = MFMA16(a[kc], bf, acc);
    }
#pragma unroll
    for (int r2 = 0; r2 < 4; r2++) {
      int o = ow + lh * 4 + r2;
      int n = n0 + ns * 16 + lr;
      float val = acc[r2] + b_qkv[o];
      if (o < 128)
        q[((size_t)b * Nvox + n) * Cch + o] = (__bf16)val;
      else if (o < 256)
        k[((size_t)b * Nvox + n) * Cch + (o - 128)] = (__bf16)val;
      else
        vt[((size_t)b * Cch + (o - 256)) * Nvox + n] = (__bf16)val;
    }
  }
}

// ---------------- K5: flash attention ----------------------------------------
// 4 waves/block, 16 q-rows/wave => 64 q rows/block; 256 blocks total.
// K tile [32][128] (stride 136), V^T tile [128][32] (stride 40), P [4][16][32] (stride 40)
__global__ __launch_bounds__(256) void attn_k(const __bf16* __restrict__ q,
                                              const __bf16* __restrict__ kk,
                                              const __bf16* __restrict__ vt,
                                              __bf16* __restrict__ h) {
  __shared__ __bf16 Kl[32][136];
  __shared__ __bf16 Vl[128][40];
  __shared__ __bf16 Pl[4][16][40];

  int b = blockIdx.x >> 7;
  int qbase = (blockIdx.x & 127) << 6;
  int w = threadIdx.x >> 6, l = threadIdx.x & 63;
  int lr = l & 15, lh = l >> 4;

  const __bf16* qb = q + (size_t)b * Nvox * Cch;
  const __bf16* kb = kk + (size_t)b * Nvox * Cch;
  const __bf16* vb = vt + (size_t)b * Cch * Nvox;

  // Q fragments held in registers for the whole kernel (A-frag: row = l&15)
  int qrow = qbase + w * 16 + lr;
  bf16x8 qa[4];
#pragma unroll
  for (int kc = 0; kc < 4; kc++)
    qa[kc] = *reinterpret_cast<const bf16x8*>(&qb[(size_t)qrow * Cch + kc * 32 + lh * 8]);

  f32x4 O[8];
#pragma unroll
  for (int cb = 0; cb < 8; cb++) O[cb] = (f32x4){0.f, 0.f, 0.f, 0.f};
  float m[4], lsum[4];
#pragma unroll
  for (int r = 0; r < 4; r++) { m[r] = -INFINITY; lsum[r] = 0.f; }

  const float k2 = 0.08838834764831845f * 1.4426950408889634f; // scale * log2(e)

  for (int t = 0; t < Nvox / 32; ++t) {
    int k0 = t * 32;
    __syncthreads(); // previous tile fully consumed before restaging
    // stage K tile: 32 rows x 128 c
    for (int i = threadIdx.x; i < 512; i += 256) {
      int row = i >> 4, ch = (i & 15) << 3;
      *reinterpret_cast<bf16x8*>(&Kl[row][ch]) =
          *reinterpret_cast<const bf16x8*>(&kb[(size_t)(k0 + row) * Cch + ch]);
    }
    // stage V^T tile: 128 c-rows x 32 kk
    for (int i = threadIdx.x; i < 512; i += 256) {
      int row = i >> 2, ch = (i & 3) << 3;
      *reinterpret_cast<bf16x8*>(&Vl[row][ch]) =
          *reinterpret_cast<const bf16x8*>(&vb[(size_t)row * Nvox + k0 + ch]);
    }
    __syncthreads();

    // QK^T: two 16x16 S-tiles (k cols k0..k0+15, k0+16..k0+31)
    f32x4 s0 = {0.f, 0.f, 0.f, 0.f}, s1 = {0.f, 0.f, 0.f, 0.f};
#pragma unroll
    for (int kc = 0; kc < 4; kc++) {
      bf16x8 kb0 = *reinterpret_cast<const bf16x8*>(&Kl[lr][kc * 32 + lh * 8]);
      bf16x8 kb1 = *reinterpret_cast<const bf16x8*>(&Kl[16 + lr][kc * 32 + lh * 8]);
      s0 = MFMA16(qa[kc], kb0, s0);
      s1 = MFMA16(qa[kc], kb1, s1);
    }

    // online softmax; D layout: q row = lh*4+r, k col = l&15 (+16 for tile 1)
    float tm[4];
#pragma unroll
    for (int r = 0; r < 4; r++) tm[r] = fmaxf(s0[r], s1[r]);
#pragma unroll
    for (int off = 1; off < 16; off <<= 1) {
#pragma unroll
      for (int r = 0; r < 4; r++) tm[r] = fmaxf(tm[r], __shfl_xor(tm[r], off));
    }
    float al[4], p0[4], p1[4], rs[4];
#pragma unroll
    for (int r = 0; r < 4; r++) {
      float mn = fmaxf(m[r], tm[r]);
      al[r] = __builtin_amdgcn_exp2f(k2 * (m[r] - mn));
      m[r] = mn;
      p0[r] = __builtin_amdgcn_exp2f(k2 * (s0[r] - mn));
      p1[r] = __builtin_amdgcn_exp2f(k2 * (s1[r] - mn));
      rs[r] = p0[r] + p1[r];
    }
#pragma unroll
    for (int off = 1; off < 16; off <<= 1) {
#pragma unroll
      for (int r = 0; r < 4; r++) rs[r] += __shfl_xor(rs[r], off);
    }
#pragma unroll
    for (int r = 0; r < 4; r++) lsum[r] = lsum[r] * al[r] + rs[r];
#pragma unroll
    for (int cb = 0; cb < 8; cb++) {
#pragma unroll
      for (int r = 0; r < 4; r++) O[cb][r] *= al[r];
    }
    // write P (true (q,k) indices), then read back as A-fragment
#pragma unroll
    for (int r = 0; r < 4; r++) {
      Pl[w][lh * 4 + r][lr] = (__bf16)p0[r];
      Pl[w][lh * 4 + r][16 + lr] = (__bf16)p1[r];
    }
    bf16x8 pa = *reinterpret_cast<const bf16x8*>(&Pl[w][lr][lh * 8]);
#pragma unroll
    for (int cb = 0; cb < 8; cb++) {
      bf16x8 vf = *reinterpret_cast<const bf16x8*>(&Vl[cb * 16 + lr][lh * 8]);
      O[cb] = MFMA16(pa, vf, O[cb]);
    }
  }

  // epilogue: normalize and store h[b][n][c] bf16
  float inv[4];
#pragma unroll
  for (int r = 0; r < 4; r++) inv[r] = 1.f / lsum[r];
  __bf16* hb = h + (size_t)b * Nvox * Cch;
#pragma unroll
  for (int cb = 0; cb < 8; cb++) {
#pragma unroll
    for (int r = 0; r < 4; r++) {
      hb[(size_t)(qbase + w * 16 + lh * 4 + r) * Cch + cb * 16 + lr] =
          (__bf16)(O[cb][r] * inv[r]);
    }
  }
}

// ---------------- K6: proj GEMM + bias + residual ----------------------------
__global__ __launch_bounds__(256) void proj_k(const __bf16* __restrict__ h,
                                              const __bf16* __restrict__ wp,
                                              const float* __restrict__ b_proj,
                                              const float* __restrict__ x,
                                              float* __restrict__ out) {
  int id = blockIdx.x;            // 2 * 2 * 128
  int b = id >> 8;
  int co0 = ((id >> 7) & 1) * 64;
  int n0 = (id & 127) * 64;
  int w = threadIdx.x >> 6, l = threadIdx.x & 63;
  int lr = l & 15, lh = l >> 4;
  int cow = co0 + w * 16;

  bf16x8 a[4];
#pragma unroll
  for (int kc = 0; kc < 4; kc++)
    a[kc] = *reinterpret_cast<const bf16x8*>(&wp[(size_t)(cow + lr) * 128 + kc * 32 + lh * 8]);

  const __bf16* hb = h + (size_t)b * Nvox * Cch;
#pragma unroll
  for (int ns = 0; ns < 4; ns++) {
    f32x4 acc = {0.f, 0.f, 0.f, 0.f};
#pragma unroll
    for (int kc = 0; kc < 4; kc++) {
      bf16x8 bf = *reinterpret_cast<const bf16x8*>(
          &hb[(size_t)(n0 + ns * 16 + lr) * Cch + kc * 32 + lh * 8]);
      acc = MFMA16(a[kc], bf, acc);
    }
#pragma unroll
    for (int r2 = 0; r2 < 4; r2++) {
      int co = cow + lh * 4 + r2;
      int n = n0 + ns * 16 + lr;
      size_t idx = ((size_t)b * Cch + co) * Nvox + n;
      out[idx] = x[idx] + b_proj[co] + acc[r2];
    }
  }
}

extern "C" void kernel_launch(void* const* d_in, const int* in_sizes, int n_in,
                              void* d_out, int out_size, void* d_ws, size_t ws_size,
                              hipStream_t stream) {
  const float* x      = (const float*)d_in[0];
  const float* gamma  = (const float*)d_in[1];
  const float* beta   = (const float*)d_in[2];
  const float* w_qkv  = (const float*)d_in[3];
  const float* b_qkv  = (const float*)d_in[4];
  const float* w_proj = (const float*)d_in[5];
  const float* b_proj = (const float*)d_in[6];
  float* out = (float*)d_out;

  char* ws = (char*)d_ws;
  float*  stats = (float*)ws;                              // 128 B
  __bf16* wq_b  = (__bf16*)(ws + 256);                     // 98304 B
  __bf16* wp_b  = (__bf16*)(ws + 256 + 98304);             // 32768 B
  size_t base = 131584;                                    // 16B-aligned
  const size_t SZ = (size_t)2 * Nvox * Cch * sizeof(__bf16); // 4 MiB per tensor
  __bf16* xn  = (__bf16*)(ws + base + 0 * SZ);
  __bf16* qw  = (__bf16*)(ws + base + 1 * SZ);
  __bf16* kw  = (__bf16*)(ws + base + 2 * SZ);
  __bf16* vtw = (__bf16*)(ws + base + 3 * SZ);
  __bf16* hw  = (__bf16*)(ws + base + 4 * SZ);
  // total ws use: ~20.1 MB

  gn_stats_k<<<16, 256, 0, stream>>>(x, stats);
  conv_w_k<<<192, 256, 0, stream>>>(w_qkv, w_proj, wq_b, wp_b);
  gn_apply_k<<<256, 256, 0, stream>>>(x, gamma, beta, stats, xn);
  qkv_k<<<1536, 256, 0, stream>>>(xn, wq_b, b_qkv, qw, kw, vtw);
  attn_k<<<256, 256, 0, stream>>>(qw, kw, vtw, hw);
  proj_k<<<512, 256, 0, stream>>>(hw, wp_b, b_proj, x, out);
}

// Round 2
// 352.359 us; speedup vs baseline: 2.1130x; 2.1130x over previous
//
#include <hip/hip_runtime.h>

typedef __bf16 bf16x8 __attribute__((ext_vector_type(8)));
typedef float  f32x4  __attribute__((ext_vector_type(4)));
typedef unsigned int uint32;

#define MFMA16(a, b, c) __builtin_amdgcn_mfma_f32_16x16x32_bf16((a), (b), (c), 0, 0, 0)
// global -> LDS direct DMA, 16B per lane; dest = wave-uniform base + lane*16
#define GLL(gsrc, ldst) __builtin_amdgcn_global_load_lds( \
    (const __attribute__((address_space(1))) uint32*)(gsrc), \
    (__attribute__((address_space(3))) uint32*)(ldst), 16, 0, 0)

static constexpr int Cch = 128;   // channels
static constexpr int Nvox = 8192; // D*H*W = 8*32*32

// ---------------- K1: GroupNorm statistics: one block per (b,g), 16 blocks ----
__global__ __launch_bounds__(256) void gn_stats_k(const float* __restrict__ x,
                                                  float* __restrict__ stats) {
  const float* base = x + (size_t)blockIdx.x * 16 * Nvox;
  float s = 0.f, ss = 0.f;
  for (int i = threadIdx.x; i < 16 * Nvox; i += 256) {
    float v = base[i];
    s += v; ss += v * v;
  }
#pragma unroll
  for (int off = 32; off; off >>= 1) {
    s  += __shfl_down(s, off);
    ss += __shfl_down(ss, off);
  }
  __shared__ float rb[4], rbss[4];
  if ((threadIdx.x & 63) == 0) {
    rb[threadIdx.x >> 6] = s;
    rbss[threadIdx.x >> 6] = ss;
  }
  __syncthreads();
  if (threadIdx.x == 0) {
    float S = rb[0] + rb[1] + rb[2] + rb[3];
    float SS = rbss[0] + rbss[1] + rbss[2] + rbss[3];
    const float invn = 1.f / (16.f * Nvox);
    float mean = S * invn;
    float var = SS * invn - mean * mean;
    stats[blockIdx.x] = mean;
    stats[16 + blockIdx.x] = rsqrtf(var + 1e-5f);
  }
}

// ---------------- K2: weight f32 -> bf16 ----------------
__global__ __launch_bounds__(256) void conv_w_k(const float* __restrict__ wq,
                                                const float* __restrict__ wp,
                                                __bf16* __restrict__ wqb,
                                                __bf16* __restrict__ wpb) {
  int i = blockIdx.x * 256 + threadIdx.x;
  if (i < 384 * 128) wqb[i] = (__bf16)wq[i];
  if (i < 128 * 128) wpb[i] = (__bf16)wp[i];
}

// ---------------- K3: normalize + transpose to xn[b][n][c] (bf16) ------------
__global__ __launch_bounds__(256) void gn_apply_k(const float* __restrict__ x,
                                                  const float* __restrict__ gamma,
                                                  const float* __restrict__ beta,
                                                  const float* __restrict__ stats,
                                                  __bf16* __restrict__ xn) {
  __shared__ __bf16 t[64][136];
  int b = blockIdx.x >> 7;
  int n0 = (blockIdx.x & 127) << 6;
  const float* xb = x + (size_t)b * Cch * Nvox;
  for (int i = threadIdx.x; i < 128 * 64; i += 256) {
    int c = i >> 6, nl = i & 63;
    int g = c >> 4;
    float mean = stats[b * 8 + g];
    float rstd = stats[16 + b * 8 + g];
    float v = xb[(size_t)c * Nvox + n0 + nl];
    t[nl][c] = (__bf16)((v - mean) * rstd * gamma[c] + beta[c]);
  }
  __syncthreads();
  __bf16* outb = xn + (size_t)b * Nvox * Cch;
  for (int i = threadIdx.x; i < 64 * 16; i += 256) {
    int row = i >> 4, ch = (i & 15) << 3;
    *reinterpret_cast<bf16x8*>(&outb[(size_t)(n0 + row) * Cch + ch]) =
        *reinterpret_cast<const bf16x8*>(&t[row][ch]);
  }
}

// ---------------- K4: QKV GEMM (MFMA bf16) -----------------------------------
__global__ __launch_bounds__(256) void qkv_k(const __bf16* __restrict__ xn,
                                             const __bf16* __restrict__ wq,
                                             const float* __restrict__ b_qkv,
                                             __bf16* __restrict__ q,
                                             __bf16* __restrict__ k,
                                             __bf16* __restrict__ vt) {
  int id = blockIdx.x;               // 2 * 6 * 128 blocks
  int b = id / 768;
  int rr = id % 768;
  int o0 = (rr >> 7) * 64;
  int n0 = (rr & 127) * 64;
  int w = threadIdx.x >> 6, l = threadIdx.x & 63;
  int lr = l & 15, lh = l >> 4;
  int ow = o0 + w * 16;

  bf16x8 a[4];
#pragma unroll
  for (int kc = 0; kc < 4; kc++)
    a[kc] = *reinterpret_cast<const bf16x8*>(&wq[(size_t)(ow + lr) * 128 + kc * 32 + lh * 8]);

  const __bf16* xb = xn + (size_t)b * Nvox * Cch;
#pragma unroll
  for (int ns = 0; ns < 4; ns++) {
    f32x4 acc = {0.f, 0.f, 0.f, 0.f};
#pragma unroll
    for (int kc = 0; kc < 4; kc++) {
      bf16x8 bf = *reinterpret_cast<const bf16x8*>(
          &xb[(size_t)(n0 + ns * 16 + lr) * Cch + kc * 32 + lh * 8]);
      acc = MFMA16(a[kc], bf, acc);
    }
#pragma unroll
    for (int r2 = 0; r2 < 4; r2++) {
      int o = ow + lh * 4 + r2;
      int n = n0 + ns * 16 + lr;
      float val = acc[r2] + b_qkv[o];
      if (o < 128)
        q[((size_t)b * Nvox + n) * Cch + o] = (__bf16)val;
      else if (o < 256)
        k[((size_t)b * Nvox + n) * Cch + (o - 128)] = (__bf16)val;
      else
        vt[((size_t)b * Cch + (o - 256)) * Nvox + n] = (__bf16)val;
    }
  }
}

// ---------------- K5: flash attention v2 -------------------------------------
// 8 waves/block (512 thr). Waves 0-3: q-tiles 0..3 x k-lower-64; waves 4-7:
// same q-tiles x k-upper-64 (in-block KV split, merged at end via LDS).
// KVBLK=128 per iter, 64 iters, double-buffered K/V staged by global_load_lds
// with pre-swizzled global source; XOR-swizzled reads (byte ^= (row&7)<<4).
// LDS: buf0 K[128][256B]+V[128][256B] = 64K, buf1 = 64K, P 8x2K = 16K -> 144K.
__global__ __launch_bounds__(512, 2) void attn_k(const __bf16* __restrict__ q,
                                                 const __bf16* __restrict__ kk,
                                                 const __bf16* __restrict__ vt,
                                                 __bf16* __restrict__ h) {
  extern __shared__ char smem[];
  const int b = blockIdx.x >> 7;
  const int qbase = (blockIdx.x & 127) << 6;
  const int w = threadIdx.x >> 6;     // 0..7
  const int l = threadIdx.x & 63;
  const int lr = l & 15, lh = l >> 4;
  const int g = w >> 2, wq = w & 3;   // k-group, q-tile
  const int swl = (lr & 7) << 4;      // read-side XOR swizzle

  const __bf16* qb = q + (size_t)b * Nvox * Cch;
  const char* kbb = (const char*)(kk + (size_t)b * Nvox * Cch);  // rows 256B
  const char* vbb = (const char*)(vt + (size_t)b * Cch * Nvox);  // rows 16384B

  // Q A-fragments in registers for the whole kernel
  const int qrow = qbase + wq * 16 + lr;
  bf16x8 qa[4];
#pragma unroll
  for (int kc = 0; kc < 4; kc++)
    qa[kc] = *reinterpret_cast<const bf16x8*>(&qb[(size_t)qrow * Cch + kc * 32 + lh * 8]);

  f32x4 O[8];
#pragma unroll
  for (int cb = 0; cb < 8; cb++) O[cb] = (f32x4){0.f, 0.f, 0.f, 0.f};
  float m[4], lsum[4];
#pragma unroll
  for (int r = 0; r < 4; r++) { m[r] = -INFINITY; lsum[r] = 0.f; }

  const float k2 = 0.08838834764831845f * 1.4426950408889634f; // scale * log2(e)
  char* Pb = smem + 131072 + w * 2048; // per-wave P: [16 q][64 k] bf16, 128B rows

  const int NT = Nvox / 128;           // 64
  int cur = 0;

  // ---- staging: waves 0-3 stage K (8KB each), waves 4-7 stage V^T (8KB each)
  auto stage = [&](int t, int bsel) {
    char* base = smem + bsel * 65536;
    if (g == 0) {
      const char* kt = kbb + (size_t)t * 128 * 256;  // K rows k0..k0+127
#pragma unroll
      for (int it = 0; it < 8; ++it) {
        int ob = wq * 8192 + it * 1024;
        int o = ob + l * 16;
        int row = o >> 8, cbyte = o & 255;
        GLL(kt + row * 256 + (cbyte ^ ((row & 7) << 4)), base + ob);
      }
    } else {
      const char* vtile = vbb + (size_t)t * 256;     // V^T cols k0..k0+127
      char* vb2 = base + 32768;
#pragma unroll
      for (int it = 0; it < 8; ++it) {
        int ob = wq * 8192 + it * 1024;
        int o = ob + l * 16;
        int row = o >> 8, cbyte = o & 255;           // row = c, cbyte = klocal*2
        GLL(vtile + (size_t)row * 16384 + (cbyte ^ ((row & 7) << 4)), vb2 + ob);
      }
    }
  };

  stage(0, 0);

  for (int t = 0; t < NT; ++t) {
    __syncthreads();                 // drains vmcnt: buf[cur] ready for all
    if (t + 1 < NT) stage(t + 1, cur ^ 1);

    const char* Kb = smem + cur * 65536;
    const char* Vb = Kb + 32768;

    // ---- QK^T for this wave's 64-k half: 4 S-tiles
    f32x4 s[4];
#pragma unroll
    for (int tt = 0; tt < 4; tt++) s[tt] = (f32x4){0.f, 0.f, 0.f, 0.f};
#pragma unroll
    for (int kc = 0; kc < 4; kc++) {
      int tcol = (kc * 64 + lh * 16) ^ swl;
#pragma unroll
      for (int tt = 0; tt < 4; tt++) {
        int krow = g * 64 + tt * 16 + lr;            // (krow&7) == (lr&7)
        bf16x8 kf = *reinterpret_cast<const bf16x8*>(Kb + krow * 256 + tcol);
        s[tt] = MFMA16(qa[kc], kf, s[tt]);
      }
    }

    // ---- online softmax over this wave's 64 k (D layout: q=lh*4+r, k=16tt+lr)
    float tm[4];
#pragma unroll
    for (int r = 0; r < 4; r++)
      tm[r] = fmaxf(fmaxf(s[0][r], s[1][r]), fmaxf(s[2][r], s[3][r]));
#pragma unroll
    for (int off = 1; off < 16; off <<= 1) {
#pragma unroll
      for (int r = 0; r < 4; r++) tm[r] = fmaxf(tm[r], __shfl_xor(tm[r], off));
    }
    float al[4], p[4][4], rs[4];
#pragma unroll
    for (int r = 0; r < 4; r++) {
      float mn = fmaxf(m[r], tm[r]);
      al[r] = __builtin_amdgcn_exp2f(k2 * (m[r] - mn));
      m[r] = mn;
    }
#pragma unroll
    for (int tt = 0; tt < 4; tt++)
#pragma unroll
      for (int r = 0; r < 4; r++)
        p[tt][r] = __builtin_amdgcn_exp2f(k2 * (s[tt][r] - m[r]));
#pragma unroll
    for (int r = 0; r < 4; r++)
      rs[r] = (p[0][r] + p[1][r]) + (p[2][r] + p[3][r]);
#pragma unroll
    for (int off = 1; off < 16; off <<= 1) {
#pragma unroll
      for (int r = 0; r < 4; r++) rs[r] += __shfl_xor(rs[r], off);
    }
#pragma unroll
    for (int r = 0; r < 4; r++) lsum[r] = lsum[r] * al[r] + rs[r];
#pragma unroll
    for (int cb = 0; cb < 8; cb++)
#pragma unroll
      for (int r = 0; r < 4; r++) O[cb][r] *= al[r];

    // ---- P -> LDS (swizzled, per-wave private; no barrier needed)
#pragma unroll
    for (int tt = 0; tt < 4; tt++)
#pragma unroll
      for (int r = 0; r < 4; r++) {
        int prow = lh * 4 + r;
        *(__bf16*)(Pb + prow * 128 + ((tt * 32 + lr * 2) ^ ((prow & 7) << 4))) =
            (__bf16)p[tt][r];
      }

    // ---- PV: O += P * V for this wave's 64-k half
#pragma unroll
    for (int ch = 0; ch < 2; ch++) {
      bf16x8 pf = *reinterpret_cast<const bf16x8*>(
          Pb + lr * 128 + ((ch * 64 + lh * 16) ^ swl));
      int vcol = (g * 128 + ch * 64 + lh * 16) ^ swl;
#pragma unroll
      for (int cb = 0; cb < 8; cb++) {
        int vrow = cb * 16 + lr;                    // (vrow&7) == (lr&7)
        bf16x8 vf = *reinterpret_cast<const bf16x8*>(Vb + vrow * 256 + vcol);
        O[cb] = MFMA16(pf, vf, O[cb]);
      }
    }
    cur ^= 1;
  }

  // ---- merge the two k-halves (flash-decoding style) via LDS ----------------
  __syncthreads();                    // all compute done; tile bufs now dead
  float* ex = (float*)smem;           // 4 pairs x 64 lanes x 40 f32 = 40KB
  float* slot = ex + ((size_t)wq * 64 + l) * 40;
  if (g == 1) {
#pragma unroll
    for (int cb = 0; cb < 8; cb++) *(f32x4*)(slot + cb * 4) = O[cb];
#pragma unroll
    for (int r = 0; r < 4; r++) { slot[32 + r] = m[r]; slot[36 + r] = lsum[r]; }
  }
  __syncthreads();
  if (g == 0) {
    float e1[4], e2[4];
#pragma unroll
    for (int r = 0; r < 4; r++) {
      float m2 = slot[32 + r], l2 = slot[36 + r];
      float M = fmaxf(m[r], m2);
      e1[r] = __builtin_amdgcn_exp2f(k2 * (m[r] - M));
      e2[r] = __builtin_amdgcn_exp2f(k2 * (m2 - M));
      lsum[r] = e1[r] * lsum[r] + e2[r] * l2;
    }
    float inv[4];
#pragma unroll
    for (int r = 0; r < 4; r++) inv[r] = 1.f / lsum[r];
    __bf16* hb = h + (size_t)b * Nvox * Cch;
#pragma unroll
    for (int cb = 0; cb < 8; cb++) {
#pragma unroll
      for (int r = 0; r < 4; r++) {
        float o = e1[r] * O[cb][r] + e2[r] * slot[cb * 4 + r];
        hb[(size_t)(qbase + wq * 16 + lh * 4 + r) * Cch + cb * 16 + lr] =
            (__bf16)(o * inv[r]);
      }
    }
  }
}

// ---------------- K6: proj GEMM + bias + residual ----------------------------
__global__ __launch_bounds__(256) void proj_k(const __bf16* __restrict__ h,
                                              const __bf16* __restrict__ wp,
                                              const float* __restrict__ b_proj,
                                              const float* __restrict__ x,
                                              float* __restrict__ out) {
  int id = blockIdx.x;            // 2 * 2 * 128
  int b = id >> 8;
  int co0 = ((id >> 7) & 1) * 64;
  int n0 = (id & 127) * 64;
  int w = threadIdx.x >> 6, l = threadIdx.x & 63;
  int lr = l & 15, lh = l >> 4;
  int cow = co0 + w * 16;

  bf16x8 a[4];
#pragma unroll
  for (int kc = 0; kc < 4; kc++)
    a[kc] = *reinterpret_cast<const bf16x8*>(&wp[(size_t)(cow + lr) * 128 + kc * 32 + lh * 8]);

  const __bf16* hb = h + (size_t)b * Nvox * Cch;
#pragma unroll
  for (int ns = 0; ns < 4; ns++) {
    f32x4 acc = {0.f, 0.f, 0.f, 0.f};
#pragma unroll
    for (int kc = 0; kc < 4; kc++) {
      bf16x8 bf = *reinterpret_cast<const bf16x8*>(
          &hb[(size_t)(n0 + ns * 16 + lr) * Cch + kc * 32 + lh * 8]);
      acc = MFMA16(a[kc], bf, acc);
    }
#pragma unroll
    for (int r2 = 0; r2 < 4; r2++) {
      int co = cow + lh * 4 + r2;
      int n = n0 + ns * 16 + lr;
      size_t idx = ((size_t)b * Cch + co) * Nvox + n;
      out[idx] = x[idx] + b_proj[co] + acc[r2];
    }
  }
}

extern "C" void kernel_launch(void* const* d_in, const int* in_sizes, int n_in,
                              void* d_out, int out_size, void* d_ws, size_t ws_size,
                              hipStream_t stream) {
  const float* x      = (const float*)d_in[0];
  const float* gamma  = (const float*)d_in[1];
  const float* beta   = (const float*)d_in[2];
  const float* w_qkv  = (const float*)d_in[3];
  const float* b_qkv  = (const float*)d_in[4];
  const float* w_proj = (const float*)d_in[5];
  const float* b_proj = (const float*)d_in[6];
  float* out = (float*)d_out;

  char* ws = (char*)d_ws;
  float*  stats = (float*)ws;                              // 128 B
  __bf16* wq_b  = (__bf16*)(ws + 256);                     // 98304 B
  __bf16* wp_b  = (__bf16*)(ws + 256 + 98304);             // 32768 B
  size_t base = 131584;                                    // 16B-aligned
  const size_t SZ = (size_t)2 * Nvox * Cch * sizeof(__bf16); // 4 MiB per tensor
  __bf16* xn  = (__bf16*)(ws + base + 0 * SZ);
  __bf16* qw  = (__bf16*)(ws + base + 1 * SZ);
  __bf16* kw  = (__bf16*)(ws + base + 2 * SZ);
  __bf16* vtw = (__bf16*)(ws + base + 3 * SZ);
  __bf16* hw  = (__bf16*)(ws + base + 4 * SZ);

  // allow 144KB dynamic LDS for attn_k (no-op if already set; host-side, not a
  // stream op, so graph-capture safe)
  (void)hipFuncSetAttribute((const void*)attn_k,
                            hipFuncAttributeMaxDynamicSharedMemorySize, 147456);

  gn_stats_k<<<16, 256, 0, stream>>>(x, stats);
  conv_w_k<<<192, 256, 0, stream>>>(w_qkv, w_proj, wq_b, wp_b);
  gn_apply_k<<<256, 256, 0, stream>>>(x, gamma, beta, stats, xn);
  qkv_k<<<1536, 256, 0, stream>>>(xn, wq_b, b_qkv, qw, kw, vtw);
  attn_k<<<256, 512, 147456, stream>>>(qw, kw, vtw, hw);
  proj_k<<<512, 256, 0, stream>>>(hw, wp_b, b_proj, x, out);
}

// Round 3
// 240.255 us; speedup vs baseline: 3.0989x; 1.4666x over previous
//
#include <hip/hip_runtime.h>

typedef __bf16 bf16x8 __attribute__((ext_vector_type(8)));
typedef float  f32x4  __attribute__((ext_vector_type(4)));
typedef float  f32x16 __attribute__((ext_vector_type(16)));
typedef float  f32x2  __attribute__((ext_vector_type(2)));
typedef unsigned int uint32;
typedef unsigned int u32x4 __attribute__((ext_vector_type(4)));
typedef unsigned int u32x2 __attribute__((ext_vector_type(2)));

#define MFMA16(a, b, c) __builtin_amdgcn_mfma_f32_16x16x32_bf16((a), (b), (c), 0, 0, 0)
#define MFMA32(a, b, c) __builtin_amdgcn_mfma_f32_32x32x16_bf16((a), (b), (c), 0, 0, 0)
// global -> LDS direct DMA, 16B per lane; dest = wave-uniform base + lane*16
#define GLL(gsrc, ldst) __builtin_amdgcn_global_load_lds( \
    (const __attribute__((address_space(1))) uint32*)(gsrc), \
    (__attribute__((address_space(3))) uint32*)(ldst), 16, 0, 0)

static constexpr int Cch = 128;   // channels
static constexpr int Nvox = 8192; // D*H*W = 8*32*32

__device__ inline unsigned int pkbf(float x, float y) {
  // pack two f32 -> {lo: bf16(x), hi: bf16(y)} (memory order: x first)
  unsigned short ux = __builtin_bit_cast(unsigned short, (__bf16)x);
  unsigned short uy = __builtin_bit_cast(unsigned short, (__bf16)y);
  return (unsigned int)ux | ((unsigned int)uy << 16);
}

// ---------------- K1a: GroupNorm partial sums: 256 blocks -------------------
__global__ __launch_bounds__(256) void gn_part_k(const float* __restrict__ x,
                                                 f32x2* __restrict__ part) {
  int bg = blockIdx.x >> 4, pt = blockIdx.x & 15;
  const f32x4* xb = (const f32x4*)(x + (size_t)bg * 131072 + (size_t)pt * 8192);
  float s = 0.f, ss = 0.f;
  for (int i = threadIdx.x; i < 2048; i += 256) {
    f32x4 v = xb[i];
    s += (v.x + v.y) + (v.z + v.w);
    ss += (v.x * v.x + v.y * v.y) + (v.z * v.z + v.w * v.w);
  }
#pragma unroll
  for (int off = 32; off; off >>= 1) {
    s  += __shfl_down(s, off);
    ss += __shfl_down(ss, off);
  }
  __shared__ float rb[4], rbss[4];
  if ((threadIdx.x & 63) == 0) { rb[threadIdx.x >> 6] = s; rbss[threadIdx.x >> 6] = ss; }
  __syncthreads();
  if (threadIdx.x == 0) {
    f32x2 o; o.x = rb[0] + rb[1] + rb[2] + rb[3];
    o.y = rbss[0] + rbss[1] + rbss[2] + rbss[3];
    part[blockIdx.x] = o;
  }
}

// ---------------- K1b: GroupNorm finish: 1 block ----------------------------
__global__ __launch_bounds__(256) void gn_fin_k(const f32x2* __restrict__ part,
                                                float* __restrict__ stats) {
  int tid = threadIdx.x;
  f32x2 v = part[tid];
  float s = v.x, ss = v.y;
#pragma unroll
  for (int off = 1; off < 16; off <<= 1) {
    s += __shfl_xor(s, off);
    ss += __shfl_xor(ss, off);
  }
  if ((tid & 15) == 0) {
    int bg = tid >> 4;
    const float invn = 1.f / 131072.f;
    float mean = s * invn;
    float var = ss * invn - mean * mean;
    stats[bg] = mean;
    stats[16 + bg] = rsqrtf(var + 1e-5f);
  }
}

// ---------------- K2: weight f32 -> bf16 ----------------
__global__ __launch_bounds__(256) void conv_w_k(const float* __restrict__ wq,
                                                const float* __restrict__ wp,
                                                __bf16* __restrict__ wqb,
                                                __bf16* __restrict__ wpb) {
  int i = blockIdx.x * 256 + threadIdx.x;
  if (i < 384 * 128) wqb[i] = (__bf16)wq[i];
  if (i < 128 * 128) wpb[i] = (__bf16)wp[i];
}

// ---------------- K3: normalize + transpose to xn[b][n][c] (bf16) ------------
__global__ __launch_bounds__(256) void gn_apply_k(const float* __restrict__ x,
                                                  const float* __restrict__ gamma,
                                                  const float* __restrict__ beta,
                                                  const float* __restrict__ stats,
                                                  __bf16* __restrict__ xn) {
  __shared__ __bf16 t[64][136];
  int b = blockIdx.x >> 7;
  int n0 = (blockIdx.x & 127) << 6;
  const float* xb = x + (size_t)b * Cch * Nvox;
  for (int i = threadIdx.x; i < 128 * 64; i += 256) {
    int c = i >> 6, nl = i & 63;
    int g = c >> 4;
    float mean = stats[b * 8 + g];
    float rstd = stats[16 + b * 8 + g];
    float v = xb[(size_t)c * Nvox + n0 + nl];
    t[nl][c] = (__bf16)((v - mean) * rstd * gamma[c] + beta[c]);
  }
  __syncthreads();
  __bf16* outb = xn + (size_t)b * Nvox * Cch;
  for (int i = threadIdx.x; i < 64 * 16; i += 256) {
    int row = i >> 4, ch = (i & 15) << 3;
    *reinterpret_cast<bf16x8*>(&outb[(size_t)(n0 + row) * Cch + ch]) =
        *reinterpret_cast<const bf16x8*>(&t[row][ch]);
  }
}

// ---------------- K4: QKV GEMM (MFMA bf16) -----------------------------------
__global__ __launch_bounds__(256) void qkv_k(const __bf16* __restrict__ xn,
                                             const __bf16* __restrict__ wq,
                                             const float* __restrict__ b_qkv,
                                             __bf16* __restrict__ q,
                                             __bf16* __restrict__ k,
                                             __bf16* __restrict__ vt) {
  int id = blockIdx.x;               // 2 * 6 * 128 blocks
  int b = id / 768;
  int rr = id % 768;
  int o0 = (rr >> 7) * 64;
  int n0 = (rr & 127) * 64;
  int w = threadIdx.x >> 6, l = threadIdx.x & 63;
  int lr = l & 15, lh = l >> 4;
  int ow = o0 + w * 16;

  bf16x8 a[4];
#pragma unroll
  for (int kc = 0; kc < 4; kc++)
    a[kc] = *reinterpret_cast<const bf16x8*>(&wq[(size_t)(ow + lr) * 128 + kc * 32 + lh * 8]);

  const __bf16* xb = xn + (size_t)b * Nvox * Cch;
#pragma unroll
  for (int ns = 0; ns < 4; ns++) {
    f32x4 acc = {0.f, 0.f, 0.f, 0.f};
#pragma unroll
    for (int kc = 0; kc < 4; kc++) {
      bf16x8 bf = *reinterpret_cast<const bf16x8*>(
          &xb[(size_t)(n0 + ns * 16 + lr) * Cch + kc * 32 + lh * 8]);
      acc = MFMA16(a[kc], bf, acc);
    }
#pragma unroll
    for (int r2 = 0; r2 < 4; r2++) {
      int o = ow + lh * 4 + r2;
      int n = n0 + ns * 16 + lr;
      float val = acc[r2] + b_qkv[o];
      if (o < 128)
        q[((size_t)b * Nvox + n) * Cch + o] = (__bf16)val;
      else if (o < 256)
        k[((size_t)b * Nvox + n) * Cch + (o - 128)] = (__bf16)val;
      else
        vt[((size_t)b * Cch + (o - 256)) * Nvox + n] = (__bf16)val;
    }
  }
}

// ---------------- K5: flash attention v3 (32x32 MFMA, swapped QK^T) ----------
// 256 blocks = b(2) x kh(2) x qbb(64). 2 warps/block, q=64/warp -> QBLK=128.
// Each block processes its k-half (4096 k) in 64 iters of KVBLK=64.
// S^T = mfma(K,Q): lane col = q, so softmax is in-lane + shfl_xor(32).
// P repacked to PV B-frags fully in registers (no P LDS).
// K tile [64][256B], V^T tile [128][128B], both XOR-swizzled (^(row&7)<<4),
// staged by global_load_lds w=16 with pre-swizzled global source (involution).
// Partial (unnormalized O^T, m, l) written per half; merged by merge_k.
__global__ __launch_bounds__(128) void attn_k(const __bf16* __restrict__ q,
                                              const __bf16* __restrict__ kk,
                                              const __bf16* __restrict__ vt,
                                              __bf16* __restrict__ po0,
                                              __bf16* __restrict__ po1,
                                              f32x2* __restrict__ ml) {
  extern __shared__ char smem[];       // 64KB: K[2][16384] then V[2][16384]
  char* Kbuf = smem;
  char* Vbuf = smem + 32768;

  const int bi = blockIdx.x;
  const int kh = bi & 1;               // k-half
  const int b = (bi >> 1) & 1;         // batch
  const int qbb = bi >> 2;             // q-block within batch (0..63)
  const int w = threadIdx.x >> 6;      // warp 0..1
  const int l = threadIdx.x & 63;
  const int l31 = l & 31, h = l >> 5;
  const int sw = (l & 7) << 4;         // read-side XOR swizzle

  const char* kb = (const char*)kk + ((size_t)b * Nvox + (size_t)kh * 4096) * 256;
  const char* vb = (const char*)vt + (size_t)b * Cch * Nvox * 2;  // c-rows 16384B
  const size_t vko = (size_t)kh * 4096 * 2;  // byte offset of k-half in a c-row

  // Q B-fragments in registers: qa[sq][dc], col q = l31, k-elems h*8..+8
  const __bf16* qptr = q + ((size_t)b * Nvox + (size_t)qbb * 128 + (size_t)w * 64) * 128;
  bf16x8 qa[2][8];
#pragma unroll
  for (int sq = 0; sq < 2; sq++)
#pragma unroll
    for (int dc = 0; dc < 8; dc++)
      qa[sq][dc] = *reinterpret_cast<const bf16x8*>(
          &qptr[(size_t)(sq * 32 + l31) * 128 + dc * 16 + h * 8]);

  f32x16 O[4][2];
#pragma unroll
  for (int cb = 0; cb < 4; cb++)
#pragma unroll
    for (int sq = 0; sq < 2; sq++)
#pragma unroll
      for (int r = 0; r < 16; r++) O[cb][sq][r] = 0.f;
  float msc[2] = {-1e30f, -1e30f};
  float lsum[2] = {0.f, 0.f};

  const float k2 = 0.08838834764831845f * 1.4426950408889634f; // scale*log2e

  auto stage = [&](int t, int bs) {
    if (w == 0) {  // K tile: 64 rows x 256B
      const char* kt = kb + (size_t)t * 64 * 256;
#pragma unroll
      for (int it = 0; it < 16; ++it) {
        int o = it * 1024 + l * 16;
        int row = o >> 8, col = (o & 255) ^ ((row & 7) << 4);
        GLL(kt + (size_t)row * 256 + col, Kbuf + bs * 16384 + it * 1024);
      }
    } else {       // V^T tile: 128 c-rows x 128B (64 k)
#pragma unroll
      for (int it = 0; it < 16; ++it) {
        int o = it * 1024 + l * 16;
        int row = o >> 7, col = (o & 127) ^ ((row & 7) << 4);
        GLL(vb + (size_t)row * 16384 + vko + (size_t)t * 128 + col,
            Vbuf + bs * 16384 + it * 1024);
      }
    }
  };

  stage(0, 0);
  int cur = 0;

  for (int t = 0; t < 64; ++t) {
    __syncthreads();                   // buf[cur] staged (vmcnt drained)
    if (t + 1 < 64) stage(t + 1, cur ^ 1);

    const char* Kb = Kbuf + cur * 16384;
    const char* Vb = Vbuf + cur * 16384;

    // ---- QK^T (swapped): St[ks][sq], rows=k, cols=q -----------------------
    f32x16 St[2][2];
#pragma unroll
    for (int ks = 0; ks < 2; ks++)
#pragma unroll
      for (int sq = 0; sq < 2; sq++)
#pragma unroll
        for (int r = 0; r < 16; r++) St[ks][sq][r] = 0.f;
#pragma unroll
    for (int ks = 0; ks < 2; ks++) {
#pragma unroll
      for (int dc = 0; dc < 8; dc++) {
        bf16x8 kf = *reinterpret_cast<const bf16x8*>(
            Kb + (ks * 32 + l31) * 256 + ((dc * 32 + h * 16) ^ sw));
#pragma unroll
        for (int sq = 0; sq < 2; sq++)
          St[ks][sq] = MFMA32(kf, qa[sq][dc], St[ks][sq]);
      }
    }

    // ---- online softmax (per q = lane col) + in-register P packing --------
    u32x4 pk[2][2][2];  // [sq][ks][kc]
#pragma unroll
    for (int sq = 0; sq < 2; sq++) {
      float pm = St[0][sq][0];
#pragma unroll
      for (int ks = 0; ks < 2; ks++)
#pragma unroll
        for (int r = 0; r < 16; r++) pm = fmaxf(pm, St[ks][sq][r]);
      pm = fmaxf(pm, __shfl_xor(pm, 32));
      float pms = pm * k2;
      if (__any(pms > msc[sq] + 8.f)) {   // defer-max (T13)
        float nm = fmaxf(msc[sq], pms);
        float al = __builtin_amdgcn_exp2f(msc[sq] - nm);
        msc[sq] = nm;
        lsum[sq] *= al;
#pragma unroll
        for (int cb = 0; cb < 4; cb++)
#pragma unroll
          for (int r = 0; r < 16; r++) O[cb][sq][r] *= al;
      }
      float p[2][16];
      float rs = 0.f;
#pragma unroll
      for (int ks = 0; ks < 2; ks++)
#pragma unroll
        for (int r = 0; r < 16; r++) {
          p[ks][r] = __builtin_amdgcn_exp2f(St[ks][sq][r] * k2 - msc[sq]);
          rs += p[ks][r];
        }
      rs += __shfl_xor(rs, 32);
      lsum[sq] += rs;
      // pack to PV B-frags: regs 0..7 -> kc0 (k0-15), regs 8..15 -> kc1
#pragma unroll
      for (int ks = 0; ks < 2; ks++) {
#pragma unroll
        for (int kc = 0; kc < 2; kc++) {
          int bs = kc * 8;
          unsigned int a0 = pkbf(p[ks][bs + 0], p[ks][bs + 1]);
          unsigned int a1 = pkbf(p[ks][bs + 2], p[ks][bs + 3]);
          unsigned int b0 = pkbf(p[ks][bs + 4], p[ks][bs + 5]);
          unsigned int b1 = pkbf(p[ks][bs + 6], p[ks][bs + 7]);
          unsigned int sa0 = __shfl_xor(a0, 32), sa1 = __shfl_xor(a1, 32);
          unsigned int sb0 = __shfl_xor(b0, 32), sb1 = __shfl_xor(b1, 32);
          bool lo = (l < 32);
          u32x4 pv;
          pv[0] = lo ? a0 : sb0;
          pv[1] = lo ? a1 : sb1;
          pv[2] = lo ? sa0 : b0;
          pv[3] = lo ? sa1 : b1;
          pk[sq][ks][kc] = pv;
        }
      }
    }

    // ---- PV: O^T[c][q] += V^T-frag x P-frag --------------------------------
#pragma unroll
    for (int ks = 0; ks < 2; ks++) {
#pragma unroll
      for (int kc = 0; kc < 2; kc++) {
#pragma unroll
        for (int cb = 0; cb < 4; cb++) {
          bf16x8 vf = *reinterpret_cast<const bf16x8*>(
              Vb + (cb * 32 + l31) * 128 + ((ks * 64 + kc * 32 + h * 16) ^ sw));
#pragma unroll
          for (int sq = 0; sq < 2; sq++)
            O[cb][sq] = MFMA32(vf, __builtin_bit_cast(bf16x8, pk[sq][ks][kc]),
                               O[cb][sq]);
        }
      }
    }
    cur ^= 1;
  }

  // ---- epilogue: write unnormalized partial O^T (bf16) + (m, l) ------------
  __bf16* po = kh ? po1 : po0;
#pragma unroll
  for (int sq = 0; sq < 2; sq++) {
    int qg = b * Nvox + qbb * 128 + w * 64 + sq * 32 + l31;
#pragma unroll
    for (int cb = 0; cb < 4; cb++) {
#pragma unroll
      for (int rq = 0; rq < 4; rq++) {
        int c = cb * 32 + rq * 8 + h * 4;
        u32x2 wv;
        wv[0] = pkbf(O[cb][sq][rq * 4 + 0], O[cb][sq][rq * 4 + 1]);
        wv[1] = pkbf(O[cb][sq][rq * 4 + 2], O[cb][sq][rq * 4 + 3]);
        *reinterpret_cast<u32x2*>((char*)po + ((size_t)qg * 128 + c) * 2) = wv;
      }
    }
    if (l < 32) {
      f32x2 v; v.x = msc[sq]; v.y = lsum[sq];
      ml[(size_t)kh * 16384 + qg] = v;
    }
  }
}

// ---------------- K5b: merge the two k-halves --------------------------------
__global__ __launch_bounds__(256) void merge_k(__bf16* __restrict__ po0,
                                               const __bf16* __restrict__ po1,
                                               const f32x2* __restrict__ ml) {
  int t = blockIdx.x * 256 + threadIdx.x;   // 65536 threads
  int qg = t >> 2;
  int c0 = (t & 3) * 32;
  f32x2 A = ml[qg], B = ml[16384 + qg];
  float M = fmaxf(A.x, B.x);
  float e1 = __builtin_amdgcn_exp2f(A.x - M);
  float e2 = __builtin_amdgcn_exp2f(B.x - M);
  float L = e1 * A.y + e2 * B.y;
  float c1 = e1 / L, c2 = e2 / L;
#pragma unroll
  for (int j = 0; j < 4; j++) {
    size_t off = (size_t)qg * 128 + c0 + j * 8;
    bf16x8 v0 = *reinterpret_cast<const bf16x8*>(&po0[off]);
    bf16x8 v1 = *reinterpret_cast<const bf16x8*>(&po1[off]);
    bf16x8 o;
#pragma unroll
    for (int i = 0; i < 8; i++)
      o[i] = (__bf16)(c1 * (float)v0[i] + c2 * (float)v1[i]);
    *reinterpret_cast<bf16x8*>(&po0[off]) = o;
  }
}

// ---------------- K6: proj GEMM + bias + residual ----------------------------
__global__ __launch_bounds__(256) void proj_k(const __bf16* __restrict__ h,
                                              const __bf16* __restrict__ wp,
                                              const float* __restrict__ b_proj,
                                              const float* __restrict__ x,
                                              float* __restrict__ out) {
  int id = blockIdx.x;            // 2 * 2 * 128
  int b = id >> 8;
  int co0 = ((id >> 7) & 1) * 64;
  int n0 = (id & 127) * 64;
  int w = threadIdx.x >> 6, l = threadIdx.x & 63;
  int lr = l & 15, lh = l >> 4;
  int cow = co0 + w * 16;

  bf16x8 a[4];
#pragma unroll
  for (int kc = 0; kc < 4; kc++)
    a[kc] = *reinterpret_cast<const bf16x8*>(&wp[(size_t)(cow + lr) * 128 + kc * 32 + lh * 8]);

  const __bf16* hb = h + (size_t)b * Nvox * Cch;
#pragma unroll
  for (int ns = 0; ns < 4; ns++) {
    f32x4 acc = {0.f, 0.f, 0.f, 0.f};
#pragma unroll
    for (int kc = 0; kc < 4; kc++) {
      bf16x8 bf = *reinterpret_cast<const bf16x8*>(
          &hb[(size_t)(n0 + ns * 16 + lr) * Cch + kc * 32 + lh * 8]);
      acc = MFMA16(a[kc], bf, acc);
    }
#pragma unroll
    for (int r2 = 0; r2 < 4; r2++) {
      int co = cow + lh * 4 + r2;
      int n = n0 + ns * 16 + lr;
      size_t idx = ((size_t)b * Cch + co) * Nvox + n;
      out[idx] = x[idx] + b_proj[co] + acc[r2];
    }
  }
}

extern "C" void kernel_launch(void* const* d_in, const int* in_sizes, int n_in,
                              void* d_out, int out_size, void* d_ws, size_t ws_size,
                              hipStream_t stream) {
  const float* x      = (const float*)d_in[0];
  const float* gamma  = (const float*)d_in[1];
  const float* beta   = (const float*)d_in[2];
  const float* w_qkv  = (const float*)d_in[3];
  const float* b_qkv  = (const float*)d_in[4];
  const float* w_proj = (const float*)d_in[5];
  const float* b_proj = (const float*)d_in[6];
  float* out = (float*)d_out;

  char* ws = (char*)d_ws;
  float*  stats = (float*)ws;                      // 128 B
  f32x2*  part  = (f32x2*)(ws + 256);              // 2 KB
  __bf16* wq_b  = (__bf16*)(ws + 4096);            // 98304 B
  __bf16* wp_b  = (__bf16*)(ws + 4096 + 98304);    // 32768 B
  size_t base = 135168;
  const size_t SZ = (size_t)2 * Nvox * Cch * sizeof(__bf16); // 4 MiB
  __bf16* xn  = (__bf16*)(ws + base + 0 * SZ);     // also reused as po1
  __bf16* qw  = (__bf16*)(ws + base + 1 * SZ);
  __bf16* kw  = (__bf16*)(ws + base + 2 * SZ);
  __bf16* vtw = (__bf16*)(ws + base + 3 * SZ);
  __bf16* hw  = (__bf16*)(ws + base + 4 * SZ);     // po0, then merged h
  f32x2*  ml  = (f32x2*)(ws + base + 5 * SZ);      // 256 KB
  // total ws use: ~21.4 MB

  (void)hipFuncSetAttribute((const void*)attn_k,
                            hipFuncAttributeMaxDynamicSharedMemorySize, 65536);

  gn_part_k<<<256, 256, 0, stream>>>(x, part);
  gn_fin_k<<<1, 256, 0, stream>>>(part, stats);
  conv_w_k<<<192, 256, 0, stream>>>(w_qkv, w_proj, wq_b, wp_b);
  gn_apply_k<<<256, 256, 0, stream>>>(x, gamma, beta, stats, xn);
  qkv_k<<<1536, 256, 0, stream>>>(xn, wq_b, b_qkv, qw, kw, vtw);
  attn_k<<<256, 128, 65536, stream>>>(qw, kw, vtw, hw, xn, ml);
  merge_k<<<256, 256, 0, stream>>>(hw, xn, ml);
  proj_k<<<512, 256, 0, stream>>>(hw, wp_b, b_proj, x, out);
}